// Round 2
// baseline (108502.332 us; speedup 1.0000x reference)
//
#include <hip/hip_runtime.h>
#include <math.h>

// LstmCellRudder persistent-kernel rewrite.
// B=256, T=512, D=160 (obs128+act32), H=512, gates 4H=2048, K=672.
// Grid 256 blocks (= 64 j-groups x 4 b-groups) x 512 threads, 1 block/CU.
// Block owns 8 j (32 gate rows) x 64 batches. Weights persist in VGPRs:
// thread (jl, kq, bg) holds rows {i,f,g,o} of one j for a 42-float k-slice
// (x part bf16-packed, h part fp32 float4s). Activations stream via LDS with
// 16-distinct-address x 4-way-broadcast ds_read_b128 (12-float padded slices).
// kq(16)-reduce: DPP xor1+xor2+ror8 (VALU) + small LDS pass. c in VGPR.
// h ping-pongs in ws; per-b-group 64-block barrier via monotonic counter,
// arrival overlapped with next step's x-projection.

namespace {
constexpr int kT = 512, kNpos = 128, kNact = 32, kH = 512;

__global__ void lstm_init(const float* __restrict__ h0, const float* __restrict__ b_out,
                          float* __restrict__ hs0, unsigned* __restrict__ cnt,
                          float* __restrict__ out) {
    int i = blockIdx.x * blockDim.x + threadIdx.x;  // 131072 = B*T = B*H
    out[i] = b_out[0];
    hs0[i] = h0[i];
    if (i < 128) cnt[i] = 0u;
}

template <int C>
__device__ __forceinline__ float dpp_add(float v) {
    int t = __builtin_amdgcn_mov_dpp(__float_as_int(v), C, 0xf, 0xf, true);
    return v + __int_as_float(t);
}

__device__ __forceinline__ unsigned bf16_rne(float f) {
    unsigned u = __float_as_uint(f);
    return (u + 0x7fffu + ((u >> 16) & 1u)) >> 16;
}

__device__ __forceinline__ float sigf(float x) { return 1.0f / (1.0f + __expf(-x)); }

__global__ __launch_bounds__(512, 2) void lstm_persist(
    const float* __restrict__ obs, const float* __restrict__ act,
    const float* __restrict__ Wih, const float* __restrict__ Whh,
    const float* __restrict__ bih, const float* __restrict__ bhh,
    const float* __restrict__ Wout, const float* __restrict__ c0,
    float* __restrict__ hsA, float* __restrict__ hsB,
    unsigned* __restrict__ cnt, float* __restrict__ out) {

    // 48 KB activation tile: [64 b][16 kq][12] (x: 10 used, h: 8 used per slice)
    __shared__ __align__(16) float sm[64 * 192];
    __shared__ __align__(16) float red[2][2][8][68];  // [g&1][kqg][jl][b(+pad)]
    __shared__ float ybuf[64][9];

    const int tid = threadIdx.x;
    const int wv = tid >> 6, ln = tid & 63;
    const int bg = wv >> 1, rghi = wv & 1;     // wave: b-group(4) x row-half(2)
    const int jlo = ln >> 4, kq = ln & 15;     // lane: j-low(4) x k-slice(16)
    const int jl = rghi * 4 + jlo;             // local j in [0,8)
    const int jg = blockIdx.x & 63, bgrp = blockIdx.x >> 6;
    const int jglob = jg * 8 + jl;

    // ---- persistent weight registers ----
    float4 wh[4][4][2];   // [gate][h-tile 128][2 x float4] : 128 VGPRs
    unsigned wxp[4][5];   // bf16-packed x-weights (k-slice 10) : 20 VGPRs
#pragma unroll
    for (int g = 0; g < 4; ++g) {
        const int row = g * kH + jglob;
        const float* wr = Wih + row * 160 + kq * 10;
#pragma unroll
        for (int m = 0; m < 5; ++m)
            wxp[g][m] = bf16_rne(wr[2 * m]) | (bf16_rne(wr[2 * m + 1]) << 16);
        const float* hr = Whh + row * kH + kq * 8;
#pragma unroll
        for (int ti = 0; ti < 4; ++ti) {
            wh[g][ti][0] = *(const float4*)(hr + ti * 128);
            wh[g][ti][1] = *(const float4*)(hr + ti * 128 + 4);
        }
    }

    // ---- epilogue identity: thread -> (jle, be), owns c[be][jle] in a VGPR ----
    const int jle = tid & 7, be = tid >> 3;
    const int jeg = jg * 8 + jle;
    const int gbe = bgrp * 64 + be;
    float bias[4];
#pragma unroll
    for (int g = 0; g < 4; ++g) bias[g] = bih[g * kH + jeg] + bhh[g * kH + jeg];
    const float wout = Wout[jeg];
    float creg = c0[(size_t)gbe * kH + jeg];

    unsigned* myc = cnt + bgrp * 32;

    float acc[4][16];

    auto stage_x = [&](int tt) {
        const size_t brow = (size_t)(bgrp * 64 + ln) * kT + tt;
        const float* orow = obs + brow * kNpos;
        const float* arow = act + brow * kNact;
        float4 a0, a1, a2, a3, a4;  // 20 floats = k [wv*20, wv*20+20)
        if (wv < 6) {
            const float* p = orow + wv * 20;
            a0 = *(const float4*)(p);      a1 = *(const float4*)(p + 4);
            a2 = *(const float4*)(p + 8);  a3 = *(const float4*)(p + 12);
            a4 = *(const float4*)(p + 16);
        } else if (wv == 6) {  // obs 120..127 + act 0..11
            a0 = *(const float4*)(orow + 120); a1 = *(const float4*)(orow + 124);
            a2 = *(const float4*)(arow);       a3 = *(const float4*)(arow + 4);
            a4 = *(const float4*)(arow + 8);
        } else {               // act 12..31
            a0 = *(const float4*)(arow + 12);  a1 = *(const float4*)(arow + 16);
            a2 = *(const float4*)(arow + 20);  a3 = *(const float4*)(arow + 24);
            a4 = *(const float4*)(arow + 28);
        }
        float* dst = &sm[ln * 192 + (2 * wv) * 12];
        *(float4*)(dst + 0) = a0;                       // f0..f3   slotA
        *(float4*)(dst + 4) = a1;                       // f4..f7
        *(float2*)(dst + 8) = make_float2(a2.x, a2.y);  // f8,f9
        *(float2*)(dst + 12) = make_float2(a2.z, a2.w); // f10,f11  slotB
        *(float2*)(dst + 14) = make_float2(a3.x, a3.y);
        *(float2*)(dst + 16) = make_float2(a3.z, a3.w);
        *(float2*)(dst + 18) = make_float2(a4.x, a4.y);
        *(float2*)(dst + 20) = make_float2(a4.z, a4.w);
    };

    auto compute_x = [&]() {
        float wxf[4][10];
#pragma unroll
        for (int g = 0; g < 4; ++g)
#pragma unroll
            for (int m = 0; m < 5; ++m) {
                unsigned p = wxp[g][m];
                wxf[g][2 * m] = __uint_as_float(p << 16);
                wxf[g][2 * m + 1] = __uint_as_float(p & 0xffff0000u);
            }
#pragma unroll
        for (int bb = 0; bb < 16; ++bb) {
            const float* src = &sm[(bg * 16 + bb) * 192 + kq * 12];
            float4 v0 = *(const float4*)(src);
            float4 v1 = *(const float4*)(src + 4);
            float2 v2 = *(const float2*)(src + 8);
#pragma unroll
            for (int g = 0; g < 4; ++g) {
                float a = v0.x * wxf[g][0];
                a = fmaf(v0.y, wxf[g][1], a);
                a = fmaf(v0.z, wxf[g][2], a);
                a = fmaf(v0.w, wxf[g][3], a);
                a = fmaf(v1.x, wxf[g][4], a);
                a = fmaf(v1.y, wxf[g][5], a);
                a = fmaf(v1.z, wxf[g][6], a);
                a = fmaf(v1.w, wxf[g][7], a);
                a = fmaf(v2.x, wxf[g][8], a);
                a = fmaf(v2.y, wxf[g][9], a);
                acc[g][bb] = a;  // fresh accumulation for this step
            }
        }
    };

    // ---- x-projection for t=0 ----
    stage_x(0);
    __syncthreads();
    compute_x();
    __syncthreads();

#pragma unroll 1
    for (int t = 0; t < kT; ++t) {
        const float* hsrc = (t & 1) ? hsB : hsA;
        float* hdst = (t & 1) ? hsA : hsB;

        // ---- h phase: 4 k-tiles of 128, register-staged single LDS buffer ----
        const float* hb = hsrc + (size_t)(bgrp * 64 + ln) * kH + wv * 16;
        float4 vh0 = *(const float4*)(hb);
        float4 vh1 = *(const float4*)(hb + 4);
        float4 vh2 = *(const float4*)(hb + 8);
        float4 vh3 = *(const float4*)(hb + 12);
#pragma unroll
        for (int ti = 0; ti < 4; ++ti) {
            float* dst = &sm[ln * 192 + (2 * wv) * 12];
            *(float4*)(dst + 0) = vh0;
            *(float4*)(dst + 4) = vh1;
            *(float4*)(dst + 12) = vh2;
            *(float4*)(dst + 16) = vh3;
            __syncthreads();
            if (ti < 3) {
                const float* nb = hb + (ti + 1) * 128;
                vh0 = *(const float4*)(nb);
                vh1 = *(const float4*)(nb + 4);
                vh2 = *(const float4*)(nb + 8);
                vh3 = *(const float4*)(nb + 12);
            }
#pragma unroll
            for (int bb = 0; bb < 16; ++bb) {
                const float* src = &sm[(bg * 16 + bb) * 192 + kq * 12];
                float4 v0 = *(const float4*)(src);
                float4 v1 = *(const float4*)(src + 4);
#pragma unroll
                for (int g = 0; g < 4; ++g) {
                    float4 w0 = wh[g][ti][0], w1 = wh[g][ti][1];
                    float a = acc[g][bb];
                    a = fmaf(v0.x, w0.x, a);
                    a = fmaf(v0.y, w0.y, a);
                    a = fmaf(v0.z, w0.z, a);
                    a = fmaf(v0.w, w0.w, a);
                    a = fmaf(v1.x, w1.x, a);
                    a = fmaf(v1.y, w1.y, a);
                    a = fmaf(v1.z, w1.z, a);
                    a = fmaf(v1.w, w1.w, a);
                    acc[g][bb] = a;
                }
            }
            __syncthreads();
        }

        // ---- kq reduce: DPP butterflies (xor1, xor2, xor8-within-16) ----
#pragma unroll
        for (int g = 0; g < 4; ++g)
#pragma unroll
            for (int bb = 0; bb < 16; ++bb) {
                float v = acc[g][bb];
                v = dpp_add<0xB1>(v);   // quad_perm [1,0,3,2]  : xor 1
                v = dpp_add<0x4E>(v);   // quad_perm [2,3,0,1]  : xor 2
                v = dpp_add<0x128>(v);  // row_ror:8            : xor 8
                acc[g][bb] = v;
            }
        // lanes kq==0 hold sum over kq{0-3,8-11}; kq==4 over kq{4-7,12-15}
        const bool wrt = (kq == 0) || (kq == 4);
        const int kqg = kq >> 2;
        float gate[4];
#pragma unroll
        for (int p = 0; p < 2; ++p) {
            if (wrt) {
#pragma unroll
                for (int h = 0; h < 2; ++h) {
                    int g = 2 * p + h;
                    float* rp = &red[h][kqg][jl][bg * 16];
                    *(float4*)(rp + 0) = make_float4(acc[g][0], acc[g][1], acc[g][2], acc[g][3]);
                    *(float4*)(rp + 4) = make_float4(acc[g][4], acc[g][5], acc[g][6], acc[g][7]);
                    *(float4*)(rp + 8) = make_float4(acc[g][8], acc[g][9], acc[g][10], acc[g][11]);
                    *(float4*)(rp + 12) = make_float4(acc[g][12], acc[g][13], acc[g][14], acc[g][15]);
                }
            }
            __syncthreads();
#pragma unroll
            for (int h = 0; h < 2; ++h) {
                int g = 2 * p + h;
                gate[g] = red[h][0][jle][be] + red[h][1][jle][be] + bias[g];
            }
            __syncthreads();
        }

        // ---- epilogue: nonlinearities, c/h update, y partial ----
        float ig = sigf(gate[0]), fg = sigf(gate[1]);
        float gv = tanhf(gate[2]), ov = sigf(gate[3]);
        creg = fmaf(fg, creg, ig * gv);
        float hn = ov * tanhf(creg);
        hdst[(size_t)gbe * kH + jeg] = hn;
        ybuf[be][jle] = hn * wout;

        __threadfence();
        __syncthreads();
        if (tid < 64) {
            float s = 0.f;
#pragma unroll
            for (int q = 0; q < 8; ++q) s += ybuf[tid][q];
            atomicAdd(&out[(size_t)(bgrp * 64 + tid) * kT + t], s);
        }
        if (tid == 0) atomicAdd(myc, 1u);

        // ---- overlap: next step's x-projection while barrier settles ----
        if (t < kT - 1) {
            stage_x(t + 1);
            __syncthreads();
            compute_x();
        }

        if (tid == 0) {
            unsigned tgt = 64u * (unsigned)(t + 1);
            while (__hip_atomic_load(myc, __ATOMIC_ACQUIRE, __HIP_MEMORY_SCOPE_AGENT) < tgt)
                __builtin_amdgcn_s_sleep(2);
        }
        __syncthreads();
        __threadfence();
    }
}

}  // namespace

extern "C" void kernel_launch(void* const* d_in, const int* in_sizes, int n_in,
                              void* d_out, int out_size, void* d_ws, size_t ws_size,
                              hipStream_t stream) {
    const float* obs  = (const float*)d_in[0];
    const float* act  = (const float*)d_in[1];
    const float* Wih  = (const float*)d_in[2];
    const float* Whh  = (const float*)d_in[3];
    const float* bih  = (const float*)d_in[4];
    const float* bhh  = (const float*)d_in[5];
    const float* Wout = (const float*)d_in[6];
    const float* bout = (const float*)d_in[7];
    const float* h0   = (const float*)d_in[8];
    const float* c0   = (const float*)d_in[9];
    float* out = (float*)d_out;

    float* ws = (float*)d_ws;
    float* hsA = ws;                               // [256][512]
    float* hsB = ws + 131072;                      // [256][512]
    unsigned* cnt = (unsigned*)(ws + 262144);      // 4 counters, 128B apart

    lstm_init<<<512, 256, 0, stream>>>(h0, bout, hsA, cnt, out);
    lstm_persist<<<256, 512, 0, stream>>>(obs, act, Wih, Whh, bih, bhh, Wout, c0,
                                          hsA, hsB, cnt, out);
}

// Round 4
// 4712.989 us; speedup vs baseline: 23.0220x; 23.0220x over previous
//
#include <hip/hip_runtime.h>
#include <math.h>

// LstmCellRudder persistent MFMA kernel, round 4.
// B=256, T=512, D=160 (obs128+act32), H=512, gates 4H=2048, K=672.
// Grid 512 blocks x 256 threads (2 blocks/CU). Block: 32 gate-rows (8 j x 4
// gates) x 32 batches. Gate GEMM via mfma_f32_16x16x32_f16: weights persist
// in VGPRs as A-fragments (21 k-steps x 4 VGPR); activations (x,h) staged in
// LDS as f16, read as B-fragments (ds_read_b128, bank-uniform stride 340 dw).
// Cross-block h exchange + flags: SYSTEM-scope RELAXED atomics only (per-op
// LLC bypass; NO fences/acquire -> no L2 wb/inv storms = R2's failure; agent
// -relaxed was insufficient = R3's failure). Barrier: per-block flag words,
// wave0 polls 64 flags in parallel. c stays fp32 in VGPR.

namespace {
constexpr int kT = 512, kNpos = 128, kNact = 32, kH = 512;

typedef _Float16 v8h __attribute__((ext_vector_type(8)));
typedef _Float16 v4h __attribute__((ext_vector_type(4)));
typedef float v4f __attribute__((ext_vector_type(4)));
typedef unsigned long long ull;

__device__ __forceinline__ ull ld_sys64(const ull* p) {
    return __hip_atomic_load(p, __ATOMIC_RELAXED, __HIP_MEMORY_SCOPE_SYSTEM);
}
__device__ __forceinline__ void st_sys64(ull* p, ull v) {
    __hip_atomic_store(p, v, __ATOMIC_RELAXED, __HIP_MEMORY_SCOPE_SYSTEM);
}
__device__ __forceinline__ unsigned ld_sys32(const unsigned* p) {
    return __hip_atomic_load(p, __ATOMIC_RELAXED, __HIP_MEMORY_SCOPE_SYSTEM);
}
__device__ __forceinline__ void st_sys32(unsigned* p, unsigned v) {
    __hip_atomic_store(p, v, __ATOMIC_RELAXED, __HIP_MEMORY_SCOPE_SYSTEM);
}

__device__ __forceinline__ float sigf(float x) {
    return 1.0f / (1.0f + __expf(fminf(-x, 80.0f)));
}
__device__ __forceinline__ float tanhff(float x) {
    float e = __expf(fminf(2.0f * x, 80.0f));
    return (e - 1.0f) / (e + 1.0f);
}

__global__ void lstm_init(const float* __restrict__ h0, const float* __restrict__ b_out,
                          _Float16* __restrict__ hsA, unsigned* __restrict__ flags,
                          float* __restrict__ out) {
    int i = blockIdx.x * blockDim.x + threadIdx.x;  // 131072 = B*H = B*T
    out[i] = b_out[0];
    hsA[i] = (_Float16)h0[i];
    if (i < 512) flags[i] = 0u;
}

__global__ __launch_bounds__(256, 2) void lstm_persist(
    const float* __restrict__ obs, const float* __restrict__ act,
    const float* __restrict__ Wih, const float* __restrict__ Whh,
    const float* __restrict__ bih, const float* __restrict__ bhh,
    const float* __restrict__ Wout, const float* __restrict__ c0,
    _Float16* __restrict__ hsA, _Float16* __restrict__ hsB,
    unsigned* __restrict__ flags, float* __restrict__ out) {

    // [batch 32][k 672 f16 + pad]: row = 680 f16 = 1360 B (16B aligned)
    __shared__ __align__(16) _Float16 actT[32][680];     // 43.5 KB
    __shared__ __align__(16) float gatesL[32][33];       // 4.2 KB
    __shared__ __align__(16) _Float16 hbuf[32][8];
    __shared__ float ybuf[32][9];

    const int tid = threadIdx.x;
    const int w = tid >> 6, ln = tid & 63;   // 4 waves
    const int rt = w & 1, ct = w >> 1;       // row-tile(2) x batch-tile(2)
    const int lm = ln & 15, q = ln >> 4;     // MFMA lane decomposition
    const int jg = blockIdx.x & 63, bgrp = blockIdx.x >> 6;  // 64 j-grp x 8 b-grp

    // ---- persistent A fragments: W row rt*16+lm, k-chunk q*8, f16 ----
    v8h afrag[21];
    {
        int r = rt * 16 + lm, g = r >> 3, jl = r & 7;
        int grow = g * kH + jg * 8 + jl;
#pragma unroll
        for (int kc = 0; kc < 21; ++kc) {
            int k0 = kc * 32 + q * 8;
            const float* src = (k0 < 160) ? (Wih + grow * 160 + k0)
                                          : (Whh + (size_t)grow * kH + (k0 - 160));
            float4 A = *(const float4*)src;
            float4 Bv = *(const float4*)(src + 4);
            v8h f;
            f[0] = (_Float16)A.x;  f[1] = (_Float16)A.y;
            f[2] = (_Float16)A.z;  f[3] = (_Float16)A.w;
            f[4] = (_Float16)Bv.x; f[5] = (_Float16)Bv.y;
            f[6] = (_Float16)Bv.z; f[7] = (_Float16)Bv.w;
            afrag[kc] = f;
        }
    }
    // bias per C-lane: rows q*4+reg of the tile
    float biasv[4];
#pragma unroll
    for (int reg = 0; reg < 4; ++reg) {
        int r2 = rt * 16 + q * 4 + reg, g2 = r2 >> 3, jl2 = r2 & 7;
        biasv[reg] = bih[g2 * kH + jg * 8 + jl2] + bhh[g2 * kH + jg * 8 + jl2];
    }

    // ---- epilogue identity: thread -> (jl, b); c in VGPR ----
    const int ejl = tid >> 5, eb = tid & 31;
    const float woutv = Wout[jg * 8 + ejl];
    float creg = c0[(size_t)(bgrp * 32 + eb) * kH + jg * 8 + ejl];

    auto stage_x = [&](int tt) {
        const int xb = tid >> 3, c8 = tid & 7;  // batch(32) x 20-float chunk(8)
        const size_t brow = (size_t)(bgrp * 32 + xb) * kT + tt;
        const float* orow = obs + brow * kNpos;
        const float* arow = act + brow * kNact;
        float4 a0, a1, a2, a3, a4;
        if (c8 < 6) {
            const float* p = orow + c8 * 20;
            a0 = *(const float4*)p;        a1 = *(const float4*)(p + 4);
            a2 = *(const float4*)(p + 8);  a3 = *(const float4*)(p + 12);
            a4 = *(const float4*)(p + 16);
        } else if (c8 == 6) {  // obs 120..127 + act 0..11
            a0 = *(const float4*)(orow + 120); a1 = *(const float4*)(orow + 124);
            a2 = *(const float4*)(arow);       a3 = *(const float4*)(arow + 4);
            a4 = *(const float4*)(arow + 8);
        } else {               // act 12..31
            a0 = *(const float4*)(arow + 12);  a1 = *(const float4*)(arow + 16);
            a2 = *(const float4*)(arow + 20);  a3 = *(const float4*)(arow + 24);
            a4 = *(const float4*)(arow + 28);
        }
        _Float16* dst = &actT[xb][c8 * 20];
        v4h p0 = {(_Float16)a0.x, (_Float16)a0.y, (_Float16)a0.z, (_Float16)a0.w};
        v4h p1 = {(_Float16)a1.x, (_Float16)a1.y, (_Float16)a1.z, (_Float16)a1.w};
        v4h p2 = {(_Float16)a2.x, (_Float16)a2.y, (_Float16)a2.z, (_Float16)a2.w};
        v4h p3 = {(_Float16)a3.x, (_Float16)a3.y, (_Float16)a3.z, (_Float16)a3.w};
        v4h p4 = {(_Float16)a4.x, (_Float16)a4.y, (_Float16)a4.z, (_Float16)a4.w};
        *(v4h*)(dst + 0) = p0;  *(v4h*)(dst + 4) = p1;  *(v4h*)(dst + 8) = p2;
        *(v4h*)(dst + 12) = p3; *(v4h*)(dst + 16) = p4;
    };

    stage_x(0);

#pragma unroll 1
    for (int t = 0; t < kT; ++t) {
        const _Float16* hsrc = (t & 1) ? hsB : hsA;
        _Float16* hdst = (t & 1) ? hsA : hsB;

        // ---- stage h(t): 8 rows/wave, LLC-bypass 8B loads, f16 passthrough ----
        {
            const ull* hu = (const ull*)hsrc;
            ull u0[8], u1[8];
#pragma unroll
            for (int rr = 0; rr < 8; ++rr) {
                int row = w * 8 + rr;
                const ull* p = hu + (size_t)(bgrp * 32 + row) * 128 + ln * 2;
                u0[rr] = ld_sys64(p);
                u1[rr] = ld_sys64(p + 1);
            }
#pragma unroll
            for (int rr = 0; rr < 8; ++rr) {
                int row = w * 8 + rr;
                ull* d = (ull*)&actT[row][160 + ln * 8];
                d[0] = u0[rr];
                d[1] = u1[rr];
            }
        }
        __syncthreads();  // S0: activations staged

        // ---- MFMA: 21 k-steps of 32 over K=672 ----
        v4f accv = {biasv[0], biasv[1], biasv[2], biasv[3]};
        const _Float16* browp = &actT[ct * 16 + lm][0];
#pragma unroll
        for (int kc = 0; kc < 21; ++kc) {
            v8h bfr = *(const v8h*)(browp + kc * 32 + q * 8);
            accv = __builtin_amdgcn_mfma_f32_16x16x32_f16(afrag[kc], bfr, accv, 0, 0, 0);
        }
#pragma unroll
        for (int reg = 0; reg < 4; ++reg)
            gatesL[rt * 16 + q * 4 + reg][ct * 16 + lm] = accv[reg];
        __syncthreads();  // S1: gates complete in LDS

        if (t < kT - 1) stage_x(t + 1);  // overlap next x staging

        // ---- epilogue: 4 gates -> c,h ----
        float g0 = gatesL[0 * 8 + ejl][eb];
        float g1 = gatesL[1 * 8 + ejl][eb];
        float g2 = gatesL[2 * 8 + ejl][eb];
        float g3 = gatesL[3 * 8 + ejl][eb];
        float iv = sigf(g0), fv = sigf(g1);
        float gv = tanhff(g2), ov = sigf(g3);
        creg = fmaf(fv, creg, iv * gv);
        float hn = ov * tanhff(creg);
        hbuf[eb][ejl] = (_Float16)hn;
        ybuf[eb][ejl] = hn * woutv;
        __syncthreads();  // S2: hbuf/ybuf ready

        // ---- h publish (bypass stores), flag, y, poll ----
        if (tid < 32 && t < kT - 1) {
            ull* hq = (ull*)&hbuf[tid][0];
            ull h0v = hq[0], h1v = hq[1];
            ull* dp = (ull*)hdst + (size_t)(bgrp * 32 + tid) * 128 + jg * 2;
            st_sys64(dp, h0v);
            st_sys64(dp + 1, h1v);
        }
        if (t < kT - 1 && tid == 0) {
            asm volatile("s_waitcnt vmcnt(0)" ::: "memory");  // wave0 h-stores at LLC
            st_sys32(flags + bgrp * 64 + jg, (unsigned)(t + 1));
        }
        if (tid < 32) {
            float s = 0.f;
#pragma unroll
            for (int qq = 0; qq < 8; ++qq) s += ybuf[tid][qq];
            atomicAdd(&out[(size_t)(bgrp * 32 + tid) * kT + t], s);
        }
        if (t < kT - 1) {
            if (tid < 64) {  // wave0: parallel 64-flag poll, no acquire, no RMW
                const unsigned tgt = (unsigned)(t + 1);
                const unsigned* fp = flags + bgrp * 64 + ln;
                while (true) {
                    unsigned v = ld_sys32(fp);
                    if (__all((int)(v >= tgt))) break;
                    __builtin_amdgcn_s_sleep(8);
                }
            }
            __syncthreads();  // S3: h(t+1) visible everywhere
        }
    }
}

}  // namespace

extern "C" void kernel_launch(void* const* d_in, const int* in_sizes, int n_in,
                              void* d_out, int out_size, void* d_ws, size_t ws_size,
                              hipStream_t stream) {
    const float* obs  = (const float*)d_in[0];
    const float* act  = (const float*)d_in[1];
    const float* Wih  = (const float*)d_in[2];
    const float* Whh  = (const float*)d_in[3];
    const float* bih  = (const float*)d_in[4];
    const float* bhh  = (const float*)d_in[5];
    const float* Wout = (const float*)d_in[6];
    const float* bout = (const float*)d_in[7];
    const float* h0   = (const float*)d_in[8];
    const float* c0   = (const float*)d_in[9];
    float* out = (float*)d_out;

    char* ws = (char*)d_ws;
    _Float16* hsA = (_Float16*)ws;                     // [256][512] f16 = 256 KB
    _Float16* hsB = (_Float16*)(ws + 262144);          // [256][512] f16
    unsigned* flags = (unsigned*)(ws + 524288);        // [512] u32

    lstm_init<<<512, 256, 0, stream>>>(h0, bout, hsA, flags, out);
    lstm_persist<<<512, 256, 0, stream>>>(obs, act, Wih, Whh, bih, bhh, Wout, c0,
                                          hsA, hsB, flags, out);
}

// Round 5
// 2441.514 us; speedup vs baseline: 44.4406x; 1.9304x over previous
//
#include <hip/hip_runtime.h>
#include <math.h>

// LstmCellRudder persistent MFMA kernel, round 5.
// B=256, T=512, D=160 (obs128+act32), H=512, gates 4H=2048, K=672.
// Grid 256 blocks x 512 threads (1 block/CU). 16 bgrps x 16 blocks.
// Block: 32 j (128 gate rows) x 16 batches. mfma_f32_16x16x32_f16, weights
// persistent in VGPRs (21 x v8h A-frags per thread). Activations staged f16
// in LDS. Cross-block h exchange: SYSTEM-scope RELAXED atomics only (verified
// recipe from R4; fences/acquire = L2 wb/inv storm, agent-relaxed = stale).
// 16-block barrier via per-block flag words. y computed locally per block
// (one designated batch) from the staged h -> no atomics on out.

namespace {
constexpr int kT = 512, kNpos = 128, kNact = 32, kH = 512;

typedef _Float16 v8h __attribute__((ext_vector_type(8)));
typedef _Float16 v4h __attribute__((ext_vector_type(4)));
typedef float v4f __attribute__((ext_vector_type(4)));
typedef unsigned long long ull;

__device__ __forceinline__ ull ld_sys64(const ull* p) {
    return __hip_atomic_load(p, __ATOMIC_RELAXED, __HIP_MEMORY_SCOPE_SYSTEM);
}
__device__ __forceinline__ void st_sys64(ull* p, ull v) {
    __hip_atomic_store(p, v, __ATOMIC_RELAXED, __HIP_MEMORY_SCOPE_SYSTEM);
}
__device__ __forceinline__ unsigned ld_sys32(const unsigned* p) {
    return __hip_atomic_load(p, __ATOMIC_RELAXED, __HIP_MEMORY_SCOPE_SYSTEM);
}
__device__ __forceinline__ void st_sys32(unsigned* p, unsigned v) {
    __hip_atomic_store(p, v, __ATOMIC_RELAXED, __HIP_MEMORY_SCOPE_SYSTEM);
}

__device__ __forceinline__ float sigf(float x) {
    return 1.0f / (1.0f + __expf(fminf(-x, 80.0f)));
}
__device__ __forceinline__ float tanhff(float x) {
    float e = __expf(fminf(2.0f * x, 80.0f));
    return (e - 1.0f) / (e + 1.0f);
}

__global__ void lstm_init(const float* __restrict__ h0, _Float16* __restrict__ hsA,
                          unsigned* __restrict__ flags) {
    int i = blockIdx.x * blockDim.x + threadIdx.x;  // 131072 = B*H
    hsA[i] = (_Float16)h0[i];
    if (i < 256) flags[i] = 0u;
}

__global__ __launch_bounds__(512, 2) void lstm_persist(
    const float* __restrict__ obs, const float* __restrict__ act,
    const float* __restrict__ Wih, const float* __restrict__ Whh,
    const float* __restrict__ bih, const float* __restrict__ bhh,
    const float* __restrict__ Wout, const float* __restrict__ bout_p,
    const float* __restrict__ c0,
    _Float16* __restrict__ hsA, _Float16* __restrict__ hsB,
    unsigned* __restrict__ flags, float* __restrict__ out) {

    __shared__ __align__(16) _Float16 actT[16][680];  // [b][k: 160 x + 512 h], 21.8 KB
    __shared__ __align__(16) float gatesL[128][17];   // [gate-row][b], 8.7 KB
    __shared__ __align__(16) _Float16 hbuf[16][32];   // [b][local j]
    __shared__ float ypart[8];
    __shared__ float ytail[2];

    const int tid = threadIdx.x;
    const int w = tid >> 6, ln = tid & 63;   // 8 waves = 8 row-tiles of 16
    const int lm = ln & 15, q = ln >> 4;     // MFMA lane decomposition
    const int jg = blockIdx.x & 15, bgrp = blockIdx.x >> 4;
    const int yb = bgrp * 16 + jg;           // the batch this block writes y for

    // ---- persistent A fragments: local gate row w*16+lm, k-chunk q*8 ----
    v8h afrag[21];
    {
        int r = w * 16 + lm;                  // 0..127
        int g = r >> 5, jl = r & 31;
        int grow = g * kH + jg * 32 + jl;
#pragma unroll
        for (int kc = 0; kc < 21; ++kc) {
            int k0 = kc * 32 + q * 8;
            const float* src = (k0 < 160) ? (Wih + grow * 160 + k0)
                                          : (Whh + (size_t)grow * kH + (k0 - 160));
            float4 A = *(const float4*)src;
            float4 Bv = *(const float4*)(src + 4);
            v8h f;
            f[0] = (_Float16)A.x;  f[1] = (_Float16)A.y;
            f[2] = (_Float16)A.z;  f[3] = (_Float16)A.w;
            f[4] = (_Float16)Bv.x; f[5] = (_Float16)Bv.y;
            f[6] = (_Float16)Bv.z; f[7] = (_Float16)Bv.w;
            afrag[kc] = f;
        }
    }
    float biasv[4];
#pragma unroll
    for (int reg = 0; reg < 4; ++reg) {
        int r2 = w * 16 + q * 4 + reg, g2 = r2 >> 5, jl2 = r2 & 31;
        biasv[reg] = bih[g2 * kH + jg * 32 + jl2] + bhh[g2 * kH + jg * 32 + jl2];
    }

    // ---- epilogue identity: thread -> (ej local j 0..31, eb batch 0..15) ----
    const int ej = tid >> 4, eb = tid & 15;
    float creg = c0[(size_t)(bgrp * 16 + eb) * kH + jg * 32 + ej];
    const float woutv = Wout[tid];            // in-loop y: tid == h index
    float4 wout4 = make_float4(0.f, 0.f, 0.f, 0.f);
    if (tid < 128) wout4 = *(const float4*)(Wout + tid * 4);
    const float bout0 = bout_p[0];

    auto stage_x = [&](int tt) {
        if (tid < 128) {
            const int xb = tid >> 3, c8 = tid & 7;  // batch(16) x 20-float chunk(8)
            const size_t brow = (size_t)(bgrp * 16 + xb) * kT + tt;
            const float* orow = obs + brow * kNpos;
            const float* arow = act + brow * kNact;
            float4 a0, a1, a2, a3, a4;
            if (c8 < 6) {
                const float* p = orow + c8 * 20;
                a0 = *(const float4*)p;        a1 = *(const float4*)(p + 4);
                a2 = *(const float4*)(p + 8);  a3 = *(const float4*)(p + 12);
                a4 = *(const float4*)(p + 16);
            } else if (c8 == 6) {  // obs 120..127 + act 0..11
                a0 = *(const float4*)(orow + 120); a1 = *(const float4*)(orow + 124);
                a2 = *(const float4*)(arow);       a3 = *(const float4*)(arow + 4);
                a4 = *(const float4*)(arow + 8);
            } else {               // act 12..31
                a0 = *(const float4*)(arow + 12);  a1 = *(const float4*)(arow + 16);
                a2 = *(const float4*)(arow + 20);  a3 = *(const float4*)(arow + 24);
                a4 = *(const float4*)(arow + 28);
            }
            _Float16* dst = &actT[xb][c8 * 20];
            v4h p0 = {(_Float16)a0.x, (_Float16)a0.y, (_Float16)a0.z, (_Float16)a0.w};
            v4h p1 = {(_Float16)a1.x, (_Float16)a1.y, (_Float16)a1.z, (_Float16)a1.w};
            v4h p2 = {(_Float16)a2.x, (_Float16)a2.y, (_Float16)a2.z, (_Float16)a2.w};
            v4h p3 = {(_Float16)a3.x, (_Float16)a3.y, (_Float16)a3.z, (_Float16)a3.w};
            v4h p4 = {(_Float16)a4.x, (_Float16)a4.y, (_Float16)a4.z, (_Float16)a4.w};
            *(v4h*)(dst + 0) = p0;  *(v4h*)(dst + 4) = p1;  *(v4h*)(dst + 8) = p2;
            *(v4h*)(dst + 12) = p3; *(v4h*)(dst + 16) = p4;
        }
    };

    stage_x(0);
    __syncthreads();

#pragma unroll 1
    for (int t = 0; t < kT; ++t) {
        const _Float16* hsrc = (t & 1) ? hsB : hsA;
        _Float16* hdst = (t & 1) ? hsA : hsB;

        // ---- x-part MFMA (no dependency on the exchange) ----
        v4f accv = {biasv[0], biasv[1], biasv[2], biasv[3]};
        const _Float16* brow = &actT[lm][0];
#pragma unroll
        for (int kc = 0; kc < 5; ++kc) {
            v8h bfr = *(const v8h*)(brow + kc * 32 + q * 8);
            accv = __builtin_amdgcn_mfma_f32_16x16x32_f16(afrag[kc], bfr, accv, 0, 0, 0);
        }

        // ---- wave0: poll the 16 flags (h_state(t) published) ----
        if (t > 0 && tid < 64) {
            const unsigned tgt = (unsigned)t;
            const unsigned* fp = flags + bgrp * 16 + (ln & 15);
            while (true) {
                unsigned v = ld_sys32(fp);
                if (__all((int)(v >= tgt))) break;
                __builtin_amdgcn_s_sleep(2);
            }
        }
        __syncthreads();  // P

        // ---- stage h(t): coalesced 8B system loads -> LDS ----
        {
            const int b = tid >> 5, p = tid & 31;
            const ull* srcp = (const ull*)(hsrc + (size_t)(bgrp * 16 + b) * kH);
            ull u0 = ld_sys64(srcp + p);
            ull u1 = ld_sys64(srcp + 32 + p);
            ull u2 = ld_sys64(srcp + 64 + p);
            ull u3 = ld_sys64(srcp + 96 + p);
            ull* d = (ull*)&actT[b][160];
            d[p] = u0; d[32 + p] = u1; d[64 + p] = u2; d[96 + p] = u3;
        }
        __syncthreads();  // S0

        // ---- y(t-1) partial: designated batch jg, h index = tid ----
        if (t > 0) {
            float p = (float)actT[jg][160 + tid] * woutv;
#pragma unroll
            for (int s = 32; s; s >>= 1) p += __shfl_xor(p, s);
            if (ln == 0) ypart[w] = p;
        }

        // ---- h-part MFMA: kc 5..20 over K=512 ----
#pragma unroll
        for (int kc = 5; kc < 21; ++kc) {
            v8h bfr = *(const v8h*)(brow + kc * 32 + q * 8);
            accv = __builtin_amdgcn_mfma_f32_16x16x32_f16(afrag[kc], bfr, accv, 0, 0, 0);
        }
#pragma unroll
        for (int reg = 0; reg < 4; ++reg)
            gatesL[w * 16 + q * 4 + reg][lm] = accv[reg];
        __syncthreads();  // S1

        if (t > 0 && tid == 0) {
            float s = bout0;
#pragma unroll
            for (int k = 0; k < 8; ++k) s += ypart[k];
            out[(size_t)yb * kT + (t - 1)] = s;
        }

        if (t < kT - 1) stage_x(t + 1);  // overlap next x staging

        // ---- epilogue: 4 gates -> c,h ----
        float g0 = gatesL[0 * 32 + ej][eb];
        float g1 = gatesL[1 * 32 + ej][eb];
        float g2 = gatesL[2 * 32 + ej][eb];
        float g3 = gatesL[3 * 32 + ej][eb];
        float iv = sigf(g0), fv = sigf(g1);
        float gv = tanhff(g2), ov = sigf(g3);
        creg = fmaf(fv, creg, iv * gv);
        float hn = ov * tanhff(creg);
        hbuf[eb][ej] = (_Float16)hn;
        __syncthreads();  // S2 (hbuf + staged x complete)

        // ---- publish h(t+1): wave0, 2 x 8B bypass stores per lane ----
        if (w == 0) {
            const int pb = ln >> 2, pc = ln & 3;
            const ull* s = (const ull*)&hbuf[pb][pc * 8];
            ull* dp = (ull*)(hdst + (size_t)(bgrp * 16 + pb) * kH + jg * 32 + pc * 8);
            st_sys64(dp, s[0]);
            st_sys64(dp + 1, s[1]);
        }
        if (tid == 0) {
            asm volatile("s_waitcnt vmcnt(0)" ::: "memory");  // h stores at LLC
            st_sys32(flags + bgrp * 16 + jg, (unsigned)(t + 1));
        }
    }

    // ---- tail: y(T-1) from h(T) (t=511 wrote hsA) ----
    if (tid < 64) {
        const unsigned* fp = flags + bgrp * 16 + (ln & 15);
        while (true) {
            unsigned v = ld_sys32(fp);
            if (__all((int)(v >= (unsigned)kT))) break;
            __builtin_amdgcn_s_sleep(2);
        }
    }
    __syncthreads();
    if (tid < 128) {
        const ull* srcp = (const ull*)(hsA + (size_t)yb * kH);
        union { ull u; _Float16 h[4]; } cv;
        cv.u = ld_sys64(srcp + tid);
        float p = (float)cv.h[0] * wout4.x + (float)cv.h[1] * wout4.y +
                  (float)cv.h[2] * wout4.z + (float)cv.h[3] * wout4.w;
#pragma unroll
        for (int s = 32; s; s >>= 1) p += __shfl_xor(p, s);
        if (ln == 0) ytail[w] = p;
    }
    __syncthreads();
    if (tid == 0) out[(size_t)yb * kT + (kT - 1)] = ytail[0] + ytail[1] + bout0;
}

}  // namespace

extern "C" void kernel_launch(void* const* d_in, const int* in_sizes, int n_in,
                              void* d_out, int out_size, void* d_ws, size_t ws_size,
                              hipStream_t stream) {
    const float* obs  = (const float*)d_in[0];
    const float* act  = (const float*)d_in[1];
    const float* Wih  = (const float*)d_in[2];
    const float* Whh  = (const float*)d_in[3];
    const float* bih  = (const float*)d_in[4];
    const float* bhh  = (const float*)d_in[5];
    const float* Wout = (const float*)d_in[6];
    const float* bout = (const float*)d_in[7];
    const float* h0   = (const float*)d_in[8];
    const float* c0   = (const float*)d_in[9];
    float* out = (float*)d_out;

    char* ws = (char*)d_ws;
    _Float16* hsA = (_Float16*)ws;                 // [256][512] f16 = 256 KB
    _Float16* hsB = (_Float16*)(ws + 262144);      // [256][512] f16
    unsigned* flags = (unsigned*)(ws + 524288);    // [256] u32

    lstm_init<<<512, 256, 0, stream>>>(h0, hsA, flags);
    lstm_persist<<<256, 512, 0, stream>>>(obs, act, Wih, Whh, bih, bhh, Wout, bout,
                                          c0, hsA, hsB, flags, out);
}

// Round 6
// 2193.741 us; speedup vs baseline: 49.4600x; 1.1129x over previous
//
#include <hip/hip_runtime.h>
#include <math.h>

// LstmCellRudder persistent MFMA kernel, round 6.
// B=256, T=512, D=160 (obs128+act32), H=512, gates 4H=2048, K=672.
// Grid 256 blocks x 512 threads. 16 bgrps x 16 blocks; block = 32 j (128 gate
// rows) x 16 batches; mfma_f32_16x16x32_f16 with weights persistent in VGPRs.
// NEW: runtime XCD-aware role assignment (s_getreg HW_REG_XCC_ID + per-XCD
// slot tables + one-time global barrier). bgrps formed XCD-pure exchange h +
// flags via AGENT-scope relaxed atomics through their local L2 (~200cyc);
// leftover mixed bgrps fall back to SYSTEM-scope (LLC bypass, R4/R5 recipe).
// No fences anywhere (L2 wb/inv storm = R2 failure). Per-bgrp flag blocks are
// 256B-aligned so no line is touched at two scopes.

namespace {
constexpr int kT = 512, kNpos = 128, kNact = 32, kH = 512;

typedef _Float16 v8h __attribute__((ext_vector_type(8)));
typedef _Float16 v4h __attribute__((ext_vector_type(4)));
typedef float v4f __attribute__((ext_vector_type(4)));
typedef unsigned long long ull;

__device__ __forceinline__ ull ld64sc(const ull* p, bool sys) {
    return sys ? __hip_atomic_load(p, __ATOMIC_RELAXED, __HIP_MEMORY_SCOPE_SYSTEM)
               : __hip_atomic_load(p, __ATOMIC_RELAXED, __HIP_MEMORY_SCOPE_AGENT);
}
__device__ __forceinline__ void st64sc(ull* p, ull v, bool sys) {
    if (sys) __hip_atomic_store(p, v, __ATOMIC_RELAXED, __HIP_MEMORY_SCOPE_SYSTEM);
    else     __hip_atomic_store(p, v, __ATOMIC_RELAXED, __HIP_MEMORY_SCOPE_AGENT);
}
__device__ __forceinline__ unsigned ld32sc(const unsigned* p, bool sys) {
    return sys ? __hip_atomic_load(p, __ATOMIC_RELAXED, __HIP_MEMORY_SCOPE_SYSTEM)
               : __hip_atomic_load(p, __ATOMIC_RELAXED, __HIP_MEMORY_SCOPE_AGENT);
}
__device__ __forceinline__ void st32sc(unsigned* p, unsigned v, bool sys) {
    if (sys) __hip_atomic_store(p, v, __ATOMIC_RELAXED, __HIP_MEMORY_SCOPE_SYSTEM);
    else     __hip_atomic_store(p, v, __ATOMIC_RELAXED, __HIP_MEMORY_SCOPE_AGENT);
}
__device__ __forceinline__ unsigned ld_sys32(const unsigned* p) {
    return __hip_atomic_load(p, __ATOMIC_RELAXED, __HIP_MEMORY_SCOPE_SYSTEM);
}

__device__ __forceinline__ float sigf(float x) {
    return 1.0f / (1.0f + __expf(fminf(-x, 80.0f)));
}
__device__ __forceinline__ float tanhff(float x) {
    float e = __expf(fminf(2.0f * x, 80.0f));
    return (e - 1.0f) / (e + 1.0f);
}

__global__ void lstm_init(const float* __restrict__ h0, _Float16* __restrict__ hsA,
                          unsigned* __restrict__ ctrl) {
    int i = blockIdx.x * blockDim.x + threadIdx.x;  // 131072 = B*H
    hsA[i] = (_Float16)h0[i];
    if (i < 1152) ctrl[i] = 0u;  // flags[16*64] + regcnt[8] + regtotal
}

__global__ __launch_bounds__(512, 2) void lstm_persist(
    const float* __restrict__ obs, const float* __restrict__ act,
    const float* __restrict__ Wih, const float* __restrict__ Whh,
    const float* __restrict__ bih, const float* __restrict__ bhh,
    const float* __restrict__ Wout, const float* __restrict__ bout_p,
    const float* __restrict__ c0,
    _Float16* __restrict__ hsA, _Float16* __restrict__ hsB,
    unsigned* __restrict__ ctrl, float* __restrict__ out) {

    __shared__ __align__(16) _Float16 actT[16][680];  // [b][k: 160 x + 512 h]
    __shared__ __align__(16) float gatesL[128][17];   // [gate-row][b]
    __shared__ __align__(16) _Float16 hbuf[16][32];   // [b][local j]
    __shared__ float ypart[8];
    __shared__ float ytail[2];
    __shared__ int sh_role[3];  // bgrp, jg, sys

    const int tid = threadIdx.x;
    const int w = tid >> 6, ln = tid & 63;   // 8 waves = 8 row-tiles of 16
    const int lm = ln & 15, q = ln >> 4;     // MFMA lane decomposition

    unsigned* flags = ctrl;              // [16 bgrps][64] (256B per bgrp)
    unsigned* regcnt = ctrl + 1024;      // [8]
    unsigned* regtotal = ctrl + 1032;    // [1]

    // ---- runtime XCD-aware role negotiation (one-time) ----
    if (tid == 0) {
        // HW_REG_XCC_ID = id 20, offset 0, size 32 -> imm 20 | (31<<11)
        int x = __builtin_amdgcn_s_getreg(20 | (31 << 11)) & 7;
        unsigned slot = atomicAdd(&regcnt[x], 1u);       // device-scope RMW
        asm volatile("s_waitcnt vmcnt(0)" ::: "memory");
        atomicAdd(regtotal, 1u);
        while (ld_sys32(regtotal) < 256u) __builtin_amdgcn_s_sleep(8);
        unsigned cnt[8];
#pragma unroll
        for (int i = 0; i < 8; ++i) cnt[i] = ld_sys32(&regcnt[i]);
        int pure_base = 0, total_pure = 0, lbase = 0;
        for (int i = 0; i < 8; ++i) {
            if (i < x) { pure_base += cnt[i] >> 4; lbase += cnt[i] & 15; }
            total_pure += cnt[i] >> 4;
        }
        int px16 = (int)(cnt[x] >> 4) * 16;
        int bg, jv, sv;
        if ((int)slot < px16) {
            bg = pure_base + ((int)slot >> 4); jv = slot & 15; sv = 0;
        } else {
            int lr = lbase + ((int)slot - px16);
            bg = total_pure + (lr >> 4); jv = lr & 15; sv = 1;
        }
        sh_role[0] = bg; sh_role[1] = jv; sh_role[2] = sv;
    }
    __syncthreads();
    const int bgrp = sh_role[0], jg = sh_role[1];
    const bool sysS = sh_role[2] != 0;
    const int yb = bgrp * 16 + jg;           // the batch this block writes y for
    unsigned* myflags = flags + bgrp * 64;

    // ---- persistent A fragments: local gate row w*16+lm, k-chunk q*8 ----
    v8h afrag[21];
    {
        int r = w * 16 + lm;                  // 0..127
        int g = r >> 5, jl = r & 31;
        int grow = g * kH + jg * 32 + jl;
#pragma unroll
        for (int kc = 0; kc < 21; ++kc) {
            int k0 = kc * 32 + q * 8;
            const float* src = (k0 < 160) ? (Wih + grow * 160 + k0)
                                          : (Whh + (size_t)grow * kH + (k0 - 160));
            float4 A = *(const float4*)src;
            float4 Bv = *(const float4*)(src + 4);
            v8h f;
            f[0] = (_Float16)A.x;  f[1] = (_Float16)A.y;
            f[2] = (_Float16)A.z;  f[3] = (_Float16)A.w;
            f[4] = (_Float16)Bv.x; f[5] = (_Float16)Bv.y;
            f[6] = (_Float16)Bv.z; f[7] = (_Float16)Bv.w;
            afrag[kc] = f;
        }
    }
    float biasv[4];
#pragma unroll
    for (int reg = 0; reg < 4; ++reg) {
        int r2 = w * 16 + q * 4 + reg, g2 = r2 >> 5, jl2 = r2 & 31;
        biasv[reg] = bih[g2 * kH + jg * 32 + jl2] + bhh[g2 * kH + jg * 32 + jl2];
    }

    // ---- epilogue identity: thread -> (ej local j 0..31, eb batch 0..15) ----
    const int ej = tid >> 4, eb = tid & 15;
    float creg = c0[(size_t)(bgrp * 16 + eb) * kH + jg * 32 + ej];
    const float woutv = Wout[tid];            // in-loop y: tid == h index
    float4 wout4 = make_float4(0.f, 0.f, 0.f, 0.f);
    if (tid < 128) wout4 = *(const float4*)(Wout + tid * 4);
    const float bout0 = bout_p[0];

    auto stage_x = [&](int tt) {
        if (tid < 128) {
            const int xb = tid >> 3, c8 = tid & 7;  // batch(16) x 20-float chunk(8)
            const size_t brow = (size_t)(bgrp * 16 + xb) * kT + tt;
            const float* orow = obs + brow * kNpos;
            const float* arow = act + brow * kNact;
            float4 a0, a1, a2, a3, a4;
            if (c8 < 6) {
                const float* p = orow + c8 * 20;
                a0 = *(const float4*)p;        a1 = *(const float4*)(p + 4);
                a2 = *(const float4*)(p + 8);  a3 = *(const float4*)(p + 12);
                a4 = *(const float4*)(p + 16);
            } else if (c8 == 6) {  // obs 120..127 + act 0..11
                a0 = *(const float4*)(orow + 120); a1 = *(const float4*)(orow + 124);
                a2 = *(const float4*)(arow);       a3 = *(const float4*)(arow + 4);
                a4 = *(const float4*)(arow + 8);
            } else {               // act 12..31
                a0 = *(const float4*)(arow + 12);  a1 = *(const float4*)(arow + 16);
                a2 = *(const float4*)(arow + 20);  a3 = *(const float4*)(arow + 24);
                a4 = *(const float4*)(arow + 28);
            }
            _Float16* dst = &actT[xb][c8 * 20];
            v4h p0 = {(_Float16)a0.x, (_Float16)a0.y, (_Float16)a0.z, (_Float16)a0.w};
            v4h p1 = {(_Float16)a1.x, (_Float16)a1.y, (_Float16)a1.z, (_Float16)a1.w};
            v4h p2 = {(_Float16)a2.x, (_Float16)a2.y, (_Float16)a2.z, (_Float16)a2.w};
            v4h p3 = {(_Float16)a3.x, (_Float16)a3.y, (_Float16)a3.z, (_Float16)a3.w};
            v4h p4 = {(_Float16)a4.x, (_Float16)a4.y, (_Float16)a4.z, (_Float16)a4.w};
            *(v4h*)(dst + 0) = p0;  *(v4h*)(dst + 4) = p1;  *(v4h*)(dst + 8) = p2;
            *(v4h*)(dst + 12) = p3; *(v4h*)(dst + 16) = p4;
        }
    };

    stage_x(0);
    __syncthreads();

#pragma unroll 1
    for (int t = 0; t < kT; ++t) {
        const _Float16* hsrc = (t & 1) ? hsB : hsA;
        _Float16* hdst = (t & 1) ? hsA : hsB;

        // ---- x-part MFMA (no dependency on the exchange) ----
        v4f accv = {biasv[0], biasv[1], biasv[2], biasv[3]};
        const _Float16* brow = &actT[lm][0];
#pragma unroll
        for (int kc = 0; kc < 5; ++kc) {
            v8h bfr = *(const v8h*)(brow + kc * 32 + q * 8);
            accv = __builtin_amdgcn_mfma_f32_16x16x32_f16(afrag[kc], bfr, accv, 0, 0, 0);
        }

        // ---- wave0: poll the 16 flags (h_state(t) published) ----
        if (t > 0 && tid < 64) {
            const unsigned tgt = (unsigned)t;
            const unsigned* fp = myflags + (ln & 15);
            while (true) {
                unsigned v = ld32sc(fp, sysS);
                if (__all((int)(v >= tgt))) break;
                __builtin_amdgcn_s_sleep(1);
            }
        }
        __syncthreads();  // P

        // ---- stage h(t): coalesced 8B scoped loads -> LDS ----
        {
            const int b = tid >> 5, p = tid & 31;
            const ull* srcp = (const ull*)(hsrc + (size_t)(bgrp * 16 + b) * kH);
            ull u0 = ld64sc(srcp + p, sysS);
            ull u1 = ld64sc(srcp + 32 + p, sysS);
            ull u2 = ld64sc(srcp + 64 + p, sysS);
            ull u3 = ld64sc(srcp + 96 + p, sysS);
            ull* d = (ull*)&actT[b][160];
            d[p] = u0; d[32 + p] = u1; d[64 + p] = u2; d[96 + p] = u3;
        }
        __syncthreads();  // S0

        // ---- y(t-1) partial: designated batch jg, h index = tid ----
        if (t > 0) {
            float p = (float)actT[jg][160 + tid] * woutv;
#pragma unroll
            for (int s = 32; s; s >>= 1) p += __shfl_xor(p, s);
            if (ln == 0) ypart[w] = p;
        }

        // ---- h-part MFMA: kc 5..20 over K=512 ----
#pragma unroll
        for (int kc = 5; kc < 21; ++kc) {
            v8h bfr = *(const v8h*)(brow + kc * 32 + q * 8);
            accv = __builtin_amdgcn_mfma_f32_16x16x32_f16(afrag[kc], bfr, accv, 0, 0, 0);
        }
#pragma unroll
        for (int reg = 0; reg < 4; ++reg)
            gatesL[w * 16 + q * 4 + reg][lm] = accv[reg];
        __syncthreads();  // S1

        if (t > 0 && tid == 0) {
            float s = bout0;
#pragma unroll
            for (int k = 0; k < 8; ++k) s += ypart[k];
            out[(size_t)yb * kT + (t - 1)] = s;
        }

        if (t < kT - 1) stage_x(t + 1);  // overlap next x staging

        // ---- epilogue: 4 gates -> c,h ----
        float g0 = gatesL[0 * 32 + ej][eb];
        float g1 = gatesL[1 * 32 + ej][eb];
        float g2 = gatesL[2 * 32 + ej][eb];
        float g3 = gatesL[3 * 32 + ej][eb];
        float iv = sigf(g0), fv = sigf(g1);
        float gv = tanhff(g2), ov = sigf(g3);
        creg = fmaf(fv, creg, iv * gv);
        float hn = ov * tanhff(creg);
        hbuf[eb][ej] = (_Float16)hn;
        __syncthreads();  // S2 (hbuf + staged x complete)

        // ---- publish h(t+1): wave0, 2 x 8B scoped stores per lane ----
        if (w == 0) {
            const int pb = ln >> 2, pc = ln & 3;
            const ull* s = (const ull*)&hbuf[pb][pc * 8];
            ull* dp = (ull*)(hdst + (size_t)(bgrp * 16 + pb) * kH + jg * 32 + pc * 8);
            st64sc(dp, s[0], sysS);
            st64sc(dp + 1, s[1], sysS);
        }
        if (tid == 0) {
            asm volatile("s_waitcnt vmcnt(0)" ::: "memory");  // h stores complete
            st32sc(myflags + jg, (unsigned)(t + 1), sysS);
        }
    }

    // ---- tail: y(T-1) from h(T) (t=511 wrote hsA) ----
    if (tid < 64) {
        const unsigned* fp = myflags + (ln & 15);
        while (true) {
            unsigned v = ld32sc(fp, sysS);
            if (__all((int)(v >= (unsigned)kT))) break;
            __builtin_amdgcn_s_sleep(1);
        }
    }
    __syncthreads();
    if (tid < 128) {
        const ull* srcp = (const ull*)(hsA + (size_t)yb * kH);
        union { ull u; _Float16 h[4]; } cv;
        cv.u = ld64sc(srcp + tid, sysS);
        float p = (float)cv.h[0] * wout4.x + (float)cv.h[1] * wout4.y +
                  (float)cv.h[2] * wout4.z + (float)cv.h[3] * wout4.w;
#pragma unroll
        for (int s = 32; s; s >>= 1) p += __shfl_xor(p, s);
        if (ln == 0) ytail[w] = p;
    }
    __syncthreads();
    if (tid == 0) out[(size_t)yb * kT + (kT - 1)] = ytail[0] + ytail[1] + bout0;
}

}  // namespace

extern "C" void kernel_launch(void* const* d_in, const int* in_sizes, int n_in,
                              void* d_out, int out_size, void* d_ws, size_t ws_size,
                              hipStream_t stream) {
    const float* obs  = (const float*)d_in[0];
    const float* act  = (const float*)d_in[1];
    const float* Wih  = (const float*)d_in[2];
    const float* Whh  = (const float*)d_in[3];
    const float* bih  = (const float*)d_in[4];
    const float* bhh  = (const float*)d_in[5];
    const float* Wout = (const float*)d_in[6];
    const float* bout = (const float*)d_in[7];
    const float* h0   = (const float*)d_in[8];
    const float* c0   = (const float*)d_in[9];
    float* out = (float*)d_out;

    char* ws = (char*)d_ws;
    _Float16* hsA = (_Float16*)ws;                 // [256][512] f16 = 256 KB
    _Float16* hsB = (_Float16*)(ws + 262144);      // [256][512] f16
    unsigned* ctrl = (unsigned*)(ws + 524288);     // flags[1024] + regcnt[8] + regtotal

    lstm_init<<<512, 256, 0, stream>>>(h0, hsA, ctrl);
    lstm_persist<<<256, 512, 0, stream>>>(obs, act, Wih, Whh, bih, bhh, Wout, bout,
                                          c0, hsA, hsB, ctrl, out);
}

// Round 7
// 2053.430 us; speedup vs baseline: 52.8395x; 1.0683x over previous
//
#include <hip/hip_runtime.h>
#include <math.h>

// LstmCellRudder persistent MFMA kernel, round 7.
// B=256, T=512, D=160 (obs128+act32), H=512, gates 4H=2048, K=672.
// Grid 256 blocks x 256 THREADS (4 waves, 1 block/CU). 16 bgrps x 16 blocks
// (XCD-pure via runtime HW_REG_XCC_ID negotiation; scoped relaxed atomics:
// agent for pure bgrps, system fallback - recipe verified R4-R6).
// NEW vs R6:
//  - 4 waves x 2 row-tiles: B-fragment LDS reads halved (read once/wave,
//    feed 2 MFMAs).
//  - fragment-major XOR-swizzled LDS: k-chunk kc = 1KB block, lane ln owns
//    16B at slot (ln ^ (kc&15)) -> all fragment reads/writes are full-block
//    permutations = zero bank conflicts (R6: 1.25e8 conflict cycles).
//  - gate-interleaved tile rows (j0g0..j0g3,j1g0..): C-frag regs = the 4
//    gates of one (j,batch) -> epilogue in-register, gatesL LDS deleted,
//    3 syncthreads/step instead of 4.
//  - x global loads pre-issued before the flag poll, LDS-written after P.

namespace {
constexpr int kT = 512, kH = 512;

typedef _Float16 v8h __attribute__((ext_vector_type(8)));
typedef _Float16 v4h __attribute__((ext_vector_type(4)));
typedef float v4f __attribute__((ext_vector_type(4)));
typedef unsigned long long ull;

__device__ __forceinline__ ull ld64sc(const ull* p, bool sys) {
    return sys ? __hip_atomic_load(p, __ATOMIC_RELAXED, __HIP_MEMORY_SCOPE_SYSTEM)
               : __hip_atomic_load(p, __ATOMIC_RELAXED, __HIP_MEMORY_SCOPE_AGENT);
}
__device__ __forceinline__ void st64sc(ull* p, ull v, bool sys) {
    if (sys) __hip_atomic_store(p, v, __ATOMIC_RELAXED, __HIP_MEMORY_SCOPE_SYSTEM);
    else     __hip_atomic_store(p, v, __ATOMIC_RELAXED, __HIP_MEMORY_SCOPE_AGENT);
}
__device__ __forceinline__ unsigned ld32sc(const unsigned* p, bool sys) {
    return sys ? __hip_atomic_load(p, __ATOMIC_RELAXED, __HIP_MEMORY_SCOPE_SYSTEM)
               : __hip_atomic_load(p, __ATOMIC_RELAXED, __HIP_MEMORY_SCOPE_AGENT);
}
__device__ __forceinline__ void st32sc(unsigned* p, unsigned v, bool sys) {
    if (sys) __hip_atomic_store(p, v, __ATOMIC_RELAXED, __HIP_MEMORY_SCOPE_SYSTEM);
    else     __hip_atomic_store(p, v, __ATOMIC_RELAXED, __HIP_MEMORY_SCOPE_AGENT);
}
__device__ __forceinline__ unsigned ld_sys32(const unsigned* p) {
    return __hip_atomic_load(p, __ATOMIC_RELAXED, __HIP_MEMORY_SCOPE_SYSTEM);
}

__device__ __forceinline__ float sigf(float x) {
    return 1.0f / (1.0f + __expf(fminf(-x, 80.0f)));
}
__device__ __forceinline__ float tanhff(float x) {
    float e = __expf(fminf(2.0f * x, 80.0f));
    return (e - 1.0f) / (e + 1.0f);
}

__global__ void lstm_init(const float* __restrict__ h0, _Float16* __restrict__ hsA,
                          unsigned* __restrict__ ctrl) {
    int i = blockIdx.x * blockDim.x + threadIdx.x;  // 131072 = B*H
    hsA[i] = (_Float16)h0[i];
    if (i < 1152) ctrl[i] = 0u;  // flags[16*64] + regcnt[8] + regtotal
}

__global__ __launch_bounds__(256, 1) void lstm_persist(
    const float* __restrict__ obs, const float* __restrict__ act,
    const float* __restrict__ Wih, const float* __restrict__ Whh,
    const float* __restrict__ bih, const float* __restrict__ bhh,
    const float* __restrict__ Wout, const float* __restrict__ bout_p,
    const float* __restrict__ c0,
    _Float16* __restrict__ hsA, _Float16* __restrict__ hsB,
    unsigned* __restrict__ ctrl, float* __restrict__ out) {

    // fragment-major activation store: 21 blocks of 1KB (kc 0..4 = x, 5..20 = h)
    // lane-slot s in block kc lives at kc*1024 + s*16; logical slot for
    // (q,batch) is (q*16+batch) ^ (kc&15)  [full-block perm -> conflict-free]
    __shared__ __align__(16) char actT[21 * 1024];    // 21 KB
    __shared__ __align__(16) _Float16 hbuf[16][32];   // [batch][local j]
    __shared__ float ypart[4];
    __shared__ float ytail[2];
    __shared__ int sh_role[3];  // bgrp, jg, sys

    const int tid = threadIdx.x;
    const int w = tid >> 6, ln = tid & 63;   // 4 waves
    const int lm = ln & 15, q = ln >> 4;     // MFMA lane decomposition

    unsigned* flags = ctrl;              // [16 bgrps][64] (256B per bgrp)
    unsigned* regcnt = ctrl + 1024;      // [8]
    unsigned* regtotal = ctrl + 1032;    // [1]

    // ---- runtime XCD-aware role negotiation (one-time, verified R6) ----
    if (tid == 0) {
        int x = __builtin_amdgcn_s_getreg(20 | (31 << 11)) & 7;  // HW_REG_XCC_ID
        unsigned slot = atomicAdd(&regcnt[x], 1u);
        asm volatile("s_waitcnt vmcnt(0)" ::: "memory");
        atomicAdd(regtotal, 1u);
        while (ld_sys32(regtotal) < 256u) __builtin_amdgcn_s_sleep(8);
        unsigned cnt[8];
#pragma unroll
        for (int i = 0; i < 8; ++i) cnt[i] = ld_sys32(&regcnt[i]);
        int pure_base = 0, total_pure = 0, lbase = 0;
        for (int i = 0; i < 8; ++i) {
            if (i < x) { pure_base += cnt[i] >> 4; lbase += cnt[i] & 15; }
            total_pure += cnt[i] >> 4;
        }
        int px16 = (int)(cnt[x] >> 4) * 16;
        int bg, jv, sv;
        if ((int)slot < px16) {
            bg = pure_base + ((int)slot >> 4); jv = slot & 15; sv = 0;
        } else {
            int lr = lbase + ((int)slot - px16);
            bg = total_pure + (lr >> 4); jv = lr & 15; sv = 1;
        }
        sh_role[0] = bg; sh_role[1] = jv; sh_role[2] = sv;
    }
    __syncthreads();
    const int bgrp = sh_role[0], jg = sh_role[1];
    const bool sysS = sh_role[2] != 0;
    const int yb = bgrp * 16 + jg;
    unsigned* myflags = flags + bgrp * 64;

    // ---- persistent A fragments: 2 tiles/wave, gate-interleaved rows ----
    // tile = w*2+ti; tile row r = 4*jj + g  (jj = j-within-tile, g = gate)
    // A lane (lm,q) holds row lm, k = kc*32 + q*8 .. +7
    v8h afrag[2][21];
#pragma unroll
    for (int ti = 0; ti < 2; ++ti) {
        const int tile = w * 2 + ti;
        const int jj = lm >> 2, g = lm & 3;
        const int grow = g * kH + jg * 32 + tile * 4 + jj;
#pragma unroll
        for (int kc = 0; kc < 21; ++kc) {
            const int k0 = kc * 32 + q * 8;
            const float* src = (k0 < 160) ? (Wih + grow * 160 + k0)
                                          : (Whh + (size_t)grow * kH + (k0 - 160));
            float4 A = *(const float4*)src;
            float4 Bv = *(const float4*)(src + 4);
            v8h f;
            f[0] = (_Float16)A.x;  f[1] = (_Float16)A.y;
            f[2] = (_Float16)A.z;  f[3] = (_Float16)A.w;
            f[4] = (_Float16)Bv.x; f[5] = (_Float16)Bv.y;
            f[6] = (_Float16)Bv.z; f[7] = (_Float16)Bv.w;
            afrag[ti][kc] = f;
        }
    }
    // C-frag lane (lm,q) reg g = gate g of j = tile*4 + q, batch lm
    float biasv[2][4];
    float creg[2];
#pragma unroll
    for (int ti = 0; ti < 2; ++ti) {
        const int tile = w * 2 + ti;
        const int jloc = jg * 32 + tile * 4 + q;
#pragma unroll
        for (int g = 0; g < 4; ++g)
            biasv[ti][g] = bih[g * kH + jloc] + bhh[g * kH + jloc];
        creg[ti] = c0[(size_t)(bgrp * 16 + lm) * kH + jloc];
    }

    const float bout0 = bout_p[0];
    const float2 wout2 = *(const float2*)(Wout + 2 * tid);  // y: k = 2*tid
    float4 wout4 = make_float4(0.f, 0.f, 0.f, 0.f);
    if (tid < 128) wout4 = *(const float4*)(Wout + tid * 4);

    // x stager identity (threads 96..255; waves 1-3, clear of wave0's poll)
    const int st = tid - 96, xb = st & 15, c10 = st >> 4;
    const bool isX = (tid >= 96);
    float4 xr[4];

    auto x_load = [&](int tt) {
        if (isX) {
            const size_t brow = (size_t)(bgrp * 16 + xb) * kT + tt;
            const float* p = (c10 < 8) ? (obs + brow * 128 + c10 * 16)
                                       : (act + brow * 32 + (c10 - 8) * 16);
            xr[0] = *(const float4*)(p);
            xr[1] = *(const float4*)(p + 4);
            xr[2] = *(const float4*)(p + 8);
            xr[3] = *(const float4*)(p + 12);
        }
    };
    auto x_write = [&]() {
        if (isX) {
            const int kcx = c10 >> 1;
#pragma unroll
            for (int ii = 0; ii < 2; ++ii) {
                const int qx = (2 * c10 + ii) & 3;
                const int slot = (qx * 16 + xb) ^ kcx;
                float4 a = xr[2 * ii], b = xr[2 * ii + 1];
                v8h f;
                f[0] = (_Float16)a.x; f[1] = (_Float16)a.y;
                f[2] = (_Float16)a.z; f[3] = (_Float16)a.w;
                f[4] = (_Float16)b.x; f[5] = (_Float16)b.y;
                f[6] = (_Float16)b.z; f[7] = (_Float16)b.w;
                *(v8h*)(actT + kcx * 1024 + slot * 16) = f;
            }
        }
    };

    // ---- initial x stage (t=0) ----
    x_load(0);
    x_write();
    __syncthreads();

#pragma unroll 1
    for (int t = 0; t < kT; ++t) {
        const _Float16* hsrc = (t & 1) ? hsB : hsA;
        _Float16* hdst = (t & 1) ? hsA : hsB;

        // ---- 1. x-part MFMA (kc 0..4), B read once, feeds both tiles ----
        v4f acc0 = {biasv[0][0], biasv[0][1], biasv[0][2], biasv[0][3]};
        v4f acc1 = {biasv[1][0], biasv[1][1], biasv[1][2], biasv[1][3]};
#pragma unroll
        for (int kc = 0; kc < 5; ++kc) {
            v8h bfr = *(const v8h*)(actT + kc * 1024 + (ln ^ kc) * 16);
            acc0 = __builtin_amdgcn_mfma_f32_16x16x32_f16(afrag[0][kc], bfr, acc0, 0, 0, 0);
            acc1 = __builtin_amdgcn_mfma_f32_16x16x32_f16(afrag[1][kc], bfr, acc1, 0, 0, 0);
        }

        // ---- 2. pre-issue next x loads (waves 1-3) ----
        if (t < kT - 1) x_load(t + 1);

        // ---- 3. wave0: poll the 16 flags ----
        if (t > 0 && tid < 64) {
            const unsigned tgt = (unsigned)t;
            const unsigned* fp = myflags + (ln & 15);
            while (true) {
                unsigned v = ld32sc(fp, sysS);
                if (__all((int)(v >= tgt))) break;
                __builtin_amdgcn_s_sleep(1);
            }
        }
        __syncthreads();  // P: h(t) published everywhere; x region free

        // ---- 4. h stage (all threads) + x write (waves 1-3) ----
        {
            const int b = tid >> 4, m4 = tid & 15;
            const ull* srcp = (const ull*)(hsrc + (size_t)(bgrp * 16 + b) * kH + m4 * 32);
            ull u[8];
#pragma unroll
            for (int i = 0; i < 8; ++i) u[i] = ld64sc(srcp + i, sysS);
            const int kch = 5 + m4, cS = kch & 15;
            char* base = actT + kch * 1024;
#pragma unroll
            for (int i = 0; i < 4; ++i) {
                ull* d = (ull*)(base + ((i * 16 + b) ^ cS) * 16);
                d[0] = u[2 * i];
                d[1] = u[2 * i + 1];
            }
        }
        x_write();
        __syncthreads();  // S0: all activations staged

        // ---- 5. h-part MFMA (kc 5..20) ----
#pragma unroll
        for (int kc = 5; kc < 21; ++kc) {
            v8h bfr = *(const v8h*)(actT + kc * 1024 + (ln ^ (kc & 15)) * 16);
            acc0 = __builtin_amdgcn_mfma_f32_16x16x32_f16(afrag[0][kc], bfr, acc0, 0, 0, 0);
            acc1 = __builtin_amdgcn_mfma_f32_16x16x32_f16(afrag[1][kc], bfr, acc1, 0, 0, 0);
        }

        // ---- 6. in-register epilogue: lane holds all 4 gates of (j, batch) ----
#pragma unroll
        for (int ti = 0; ti < 2; ++ti) {
            v4f a = ti ? acc1 : acc0;
            float iv = sigf(a[0]), fv = sigf(a[1]);
            float gv = tanhff(a[2]), ov = sigf(a[3]);
            creg[ti] = fmaf(fv, creg[ti], iv * gv);
            float hn = ov * tanhff(creg[ti]);
            hbuf[lm][(w * 2 + ti) * 4 + q] = (_Float16)hn;
        }

        // ---- 7. y(t-1): dot staged h(t) with Wout (k = 2*tid, 2 values) ----
        if (t > 0) {
            const int k = 2 * tid;
            const int kch = 5 + (k >> 5), qy = (k >> 3) & 3, e = k & 7;
            const int slot = (qy * 16 + jg) ^ (kch & 15);
            union { unsigned u; _Float16 h[2]; } cv;
            cv.u = *(const unsigned*)(actT + kch * 1024 + slot * 16 + e * 2);
            float p = (float)cv.h[0] * wout2.x + (float)cv.h[1] * wout2.y;
#pragma unroll
            for (int s = 32; s; s >>= 1) p += __shfl_xor(p, s);
            if (ln == 0) ypart[w] = p;
        }
        __syncthreads();  // S2: hbuf + ypart ready

        // ---- 8. publish h(t+1) (wave0) + flag; y write (wave1) ----
        if (w == 0) {
            const int pb = ln >> 2, pc = ln & 3;
            const ull* hq = (const ull*)&hbuf[pb][pc * 8];
            ull* dp = (ull*)(hdst + (size_t)(bgrp * 16 + pb) * kH + jg * 32 + pc * 8);
            st64sc(dp, hq[0], sysS);
            st64sc(dp + 1, hq[1], sysS);
        }
        if (tid == 0) {
            asm volatile("s_waitcnt vmcnt(0)" ::: "memory");
            st32sc(myflags + jg, (unsigned)(t + 1), sysS);
        }
        if (t > 0 && tid == 64) {
            out[(size_t)yb * kT + (t - 1)] = bout0 + ypart[0] + ypart[1] + ypart[2] + ypart[3];
        }
    }

    // ---- tail: y(T-1) from h(T) (t=511 wrote hsA) ----
    if (tid < 64) {
        const unsigned* fp = myflags + (ln & 15);
        while (true) {
            unsigned v = ld32sc(fp, sysS);
            if (__all((int)(v >= (unsigned)kT))) break;
            __builtin_amdgcn_s_sleep(1);
        }
    }
    __syncthreads();
    if (tid < 128) {
        const ull* srcp = (const ull*)(hsA + (size_t)yb * kH);
        union { ull u; _Float16 h[4]; } cv;
        cv.u = ld64sc(srcp + tid, sysS);
        float p = (float)cv.h[0] * wout4.x + (float)cv.h[1] * wout4.y +
                  (float)cv.h[2] * wout4.z + (float)cv.h[3] * wout4.w;
#pragma unroll
        for (int s = 32; s; s >>= 1) p += __shfl_xor(p, s);
        if (ln == 0) ytail[w] = p;
    }
    __syncthreads();
    if (tid == 0) out[(size_t)yb * kT + (kT - 1)] = ytail[0] + ytail[1] + bout0;
}

}  // namespace

extern "C" void kernel_launch(void* const* d_in, const int* in_sizes, int n_in,
                              void* d_out, int out_size, void* d_ws, size_t ws_size,
                              hipStream_t stream) {
    const float* obs  = (const float*)d_in[0];
    const float* act  = (const float*)d_in[1];
    const float* Wih  = (const float*)d_in[2];
    const float* Whh  = (const float*)d_in[3];
    const float* bih  = (const float*)d_in[4];
    const float* bhh  = (const float*)d_in[5];
    const float* Wout = (const float*)d_in[6];
    const float* bout = (const float*)d_in[7];
    const float* h0   = (const float*)d_in[8];
    const float* c0   = (const float*)d_in[9];
    float* out = (float*)d_out;

    char* ws = (char*)d_ws;
    _Float16* hsA = (_Float16*)ws;                 // [256][512] f16 = 256 KB
    _Float16* hsB = (_Float16*)(ws + 262144);      // [256][512] f16
    unsigned* ctrl = (unsigned*)(ws + 524288);     // flags[1024] + regcnt[8] + regtotal

    lstm_init<<<512, 256, 0, stream>>>(h0, hsA, ctrl);
    lstm_persist<<<256, 256, 0, stream>>>(obs, act, Wih, Whh, bih, bhh, Wout, bout,
                                          c0, hsA, hsB, ctrl, out);
}